// Round 2
// baseline (282.928 us; speedup 1.0000x reference)
//
#include <hip/hip_runtime.h>
#include <hip/hip_bf16.h>

// RUDY routing-demand maps.
// Key identity: each net deposits wt * u(x) ⊗ v(y), where u is the bin-overlap
// profile of [xmin,xmax] (piecewise constant-ish in bin index). Its first
// difference d_u has <=4 nonzeros (at i0, i0+1, i1, i1+1). Scatter
// wt*d_u⊗d_v (<=16 cells/net/map) into a difference grid D, then one
// inclusive prefix sum per dimension reconstructs the map.
// O(nets) work instead of O(nets * bins).

#define NBX 256
#define NBY 256
#define NMAP (NBX * NBY)

__constant__ constexpr float BSX = 2.0f;
__constant__ constexpr float BSY = 2.0f;
// 1/(bin_area * UNIT_HCAP), 1/(bin_area * UNIT_VCAP)
__constant__ constexpr float INV_H = 1.0f / (4.0f * 50.0f);
__constant__ constexpr float INV_V = 1.0f / (4.0f * 40.0f);

// Cumulative overlap length of [mn,mx] with [XL, t], XL = 0.
__device__ __forceinline__ float seg_cum(float t, float mn, float mx) {
    return fminf(fmaxf(t, mn), mx) - mn;
}

// dU(i) = U(i) - U(i-1) where U(i) is the overlap of bin i with [mn,mx].
// Equals the second difference of the cumulative profile C(t)=seg_cum.
__device__ __forceinline__ float second_diff(int i, float bs, float mn, float mx) {
    float u2 = seg_cum((float)(i + 1) * bs, mn, mx);
    float u1 = seg_cum((float)(i) * bs, mn, mx);
    float u0 = seg_cum((float)(i - 1) * bs, mn, mx);
    return (u2 - u1) - (u1 - u0);
}

__global__ void __launch_bounds__(256) net_scatter(
    const float* __restrict__ pin_pos,
    const int* __restrict__ netpin_start,
    const int* __restrict__ flat_netpin,
    const float* __restrict__ net_weights,
    float2* __restrict__ D,   // interleaved {dH, dV} difference grid
    int num_nets) {
    int n = blockIdx.x * blockDim.x + threadIdx.x;
    if (n >= num_nets) return;
    int s = netpin_start[n];
    int e = netpin_start[n + 1];
    if (e <= s) return;

    float xmn = 3.0e38f, xmx = -3.0e38f, ymn = 3.0e38f, ymx = -3.0e38f;
    for (int p = s; p < e; ++p) {
        int ip = flat_netpin[p];
        float2 xy = *reinterpret_cast<const float2*>(pin_pos + 2 * (size_t)ip);
        xmn = fminf(xmn, xy.x);
        xmx = fmaxf(xmx, xy.x);
        ymn = fminf(ymn, xy.y);
        ymx = fmaxf(ymx, xy.y);
    }
    float w  = net_weights[n];
    float wh = w / (ymx - ymn);  // horizontal demand density
    float wv = w / (xmx - xmn);  // vertical demand density

    // Breakpoint bins (XL = YL = 0, bin size 2 -> *0.5)
    int i0 = (int)floorf(xmn * 0.5f);
    int i1 = (int)floorf(xmx * 0.5f);
    int j0 = (int)floorf(ymn * 0.5f);
    int j1 = (int)floorf(ymx * 0.5f);

    // Fixed 4-slot candidate lists (static indexing -> stays in registers).
    int   xi[4], yi[4];
    float dx[4], dy[4];
    xi[0] = i0; xi[1] = i0 + 1;
    xi[2] = (i1 > i0 + 1) ? i1 : -1;
    xi[3] = (i1 + 1 > i0 + 1) ? i1 + 1 : -1;
    yi[0] = j0; yi[1] = j0 + 1;
    yi[2] = (j1 > j0 + 1) ? j1 : -1;
    yi[3] = (j1 + 1 > j0 + 1) ? j1 + 1 : -1;
#pragma unroll
    for (int k = 0; k < 4; ++k) {
        dx[k] = (xi[k] >= 0 && xi[k] < NBX) ? second_diff(xi[k], BSX, xmn, xmx) : 0.0f;
        dy[k] = (yi[k] >= 0 && yi[k] < NBY) ? second_diff(yi[k], BSY, ymn, ymx) : 0.0f;
    }

#pragma unroll
    for (int a = 0; a < 4; ++a) {
#pragma unroll
        for (int b = 0; b < 4; ++b) {
            float p = dx[a] * dy[b];
            if (p != 0.0f) {
                float2* cell = &D[xi[a] * NBY + yi[b]];
                atomicAdd(&cell->x, wh * p);
                atomicAdd(&cell->y, wv * p);
            }
        }
    }
}

// Inclusive scan along y (inner dim) per row, both maps at once.
__global__ void __launch_bounds__(256) scan_rows(float2* __restrict__ D) {
    __shared__ float bh[NBY];
    __shared__ float bv[NBY];
    int row = blockIdx.x;   // x index
    int y = threadIdx.x;
    float2 v = D[row * NBY + y];
    bh[y] = v.x;
    bv[y] = v.y;
    __syncthreads();
    for (int off = 1; off < NBY; off <<= 1) {
        float ah = 0.0f, av = 0.0f;
        if (y >= off) { ah = bh[y - off]; av = bv[y - off]; }
        __syncthreads();
        bh[y] += ah;
        bv[y] += av;
        __syncthreads();
    }
    D[row * NBY + y] = make_float2(bh[y], bv[y]);
}

// Serial scan along x (one thread per column) + fused finalize.
__global__ void __launch_bounds__(256) scan_cols_finalize(
    const float2* __restrict__ D,
    const float* __restrict__ init_h,
    const float* __restrict__ init_v,
    float* __restrict__ out) {
    int y = threadIdx.x;
    float accH = 0.0f, accV = 0.0f;
    for (int x = 0; x < NBX; ++x) {
        int idx = x * NBY + y;
        float2 d = D[idx];
        accH += d.x;
        accV += d.y;
        float H = fmaf(accH, INV_H, init_h[idx]);
        float V = fmaf(accV, INV_V, init_v[idx]);
        float r = fmaxf(fabsf(H), fabsf(V));
        out[idx]            = r;
        out[idx + NMAP]     = H;
        out[idx + 2 * NMAP] = V;
    }
}

extern "C" void kernel_launch(void* const* d_in, const int* in_sizes, int n_in,
                              void* d_out, int out_size, void* d_ws, size_t ws_size,
                              hipStream_t stream) {
    const float* pin_pos      = (const float*)d_in[0];
    const int*   netpin_start = (const int*)d_in[1];
    const int*   flat_netpin  = (const int*)d_in[2];
    const float* net_weights  = (const float*)d_in[3];
    const float* init_h       = (const float*)d_in[4];
    const float* init_v       = (const float*)d_in[5];
    float* out = (float*)d_out;

    int num_nets = in_sizes[3];           // net_weights length
    float2* D = (float2*)d_ws;            // 256*256*8B = 512 KiB scratch

    hipMemsetAsync(d_ws, 0, (size_t)NMAP * sizeof(float2), stream);

    int blocks = (num_nets + 255) / 256;
    net_scatter<<<blocks, 256, 0, stream>>>(pin_pos, netpin_start, flat_netpin,
                                            net_weights, D, num_nets);
    scan_rows<<<NBX, 256, 0, stream>>>(D);
    scan_cols_finalize<<<1, 256, 0, stream>>>(D, init_h, init_v, out);
}

// Round 3
// 186.198 us; speedup vs baseline: 1.5195x; 1.5195x over previous
//
#include <hip/hip_runtime.h>
#include <hip/hip_bf16.h>

// RUDY routing-demand maps via difference-domain scatter + 2D prefix sum.
// Each net deposits wt * u(x) ⊗ v(y); the first difference of the bin-overlap
// profile u has <=4 nonzeros, so each net scatters <=16 cells into a
// difference grid D; one inclusive scan per dimension reconstructs the maps.
//
// Round-3 change: device-scope f32 atomics are performed at the memory-side
// coherence point (round-2 evidence: WRITE_SIZE 96 MB = 3.2M atomics x 32B,
// 242 us with all pipes idle -> hot-cacheline serialization). Scatter into K
// replicas of D (replica = blockIdx % K) to spread same-line traffic; fold
// replicas during the y-scan. x-scan parallelized (256 blocks) and fused with
// finalize.

#define NBX 256
#define NBY 256
#define NMAP (NBX * NBY)
#define MAXK 16

__constant__ constexpr float BSX = 2.0f;
__constant__ constexpr float BSY = 2.0f;
// 1/(bin_area * UNIT_HCAP), 1/(bin_area * UNIT_VCAP)
__constant__ constexpr float INV_H = 1.0f / (4.0f * 50.0f);
__constant__ constexpr float INV_V = 1.0f / (4.0f * 40.0f);

// Cumulative overlap length of [mn,mx] with [XL, t], XL = 0.
__device__ __forceinline__ float seg_cum(float t, float mn, float mx) {
    return fminf(fmaxf(t, mn), mx) - mn;
}

// First difference of the per-bin overlap U(i) of [mn,mx] with bin i.
__device__ __forceinline__ float second_diff(int i, float bs, float mn, float mx) {
    float u2 = seg_cum((float)(i + 1) * bs, mn, mx);
    float u1 = seg_cum((float)(i) * bs, mn, mx);
    float u0 = seg_cum((float)(i - 1) * bs, mn, mx);
    return (u2 - u1) - (u1 - u0);
}

__global__ void __launch_bounds__(256) net_scatter(
    const float* __restrict__ pin_pos,
    const int* __restrict__ netpin_start,
    const int* __restrict__ flat_netpin,
    const float* __restrict__ net_weights,
    float2* __restrict__ D,   // K replicas of interleaved {dH, dV} grid
    int num_nets, int K) {
    int n = blockIdx.x * blockDim.x + threadIdx.x;
    if (n >= num_nets) return;
    int s = netpin_start[n];
    int e = netpin_start[n + 1];
    if (e <= s) return;

    float2* __restrict__ Dr = D + (size_t)(blockIdx.x % K) * NMAP;

    float xmn = 3.0e38f, xmx = -3.0e38f, ymn = 3.0e38f, ymx = -3.0e38f;
    for (int p = s; p < e; ++p) {
        int ip = flat_netpin[p];
        float2 xy = *reinterpret_cast<const float2*>(pin_pos + 2 * (size_t)ip);
        xmn = fminf(xmn, xy.x);
        xmx = fmaxf(xmx, xy.x);
        ymn = fminf(ymn, xy.y);
        ymx = fmaxf(ymx, xy.y);
    }
    float w  = net_weights[n];
    float wh = w / (ymx - ymn);  // horizontal demand density
    float wv = w / (xmx - xmn);  // vertical demand density

    // Breakpoint bins (XL = YL = 0, bin size 2 -> *0.5)
    int i0 = (int)floorf(xmn * 0.5f);
    int i1 = (int)floorf(xmx * 0.5f);
    int j0 = (int)floorf(ymn * 0.5f);
    int j1 = (int)floorf(ymx * 0.5f);

    // Fixed 4-slot candidate lists (static indexing -> registers).
    int   xi[4], yi[4];
    float dx[4], dy[4];
    xi[0] = i0; xi[1] = i0 + 1;
    xi[2] = (i1 > i0 + 1) ? i1 : -1;
    xi[3] = (i1 + 1 > i0 + 1) ? i1 + 1 : -1;
    yi[0] = j0; yi[1] = j0 + 1;
    yi[2] = (j1 > j0 + 1) ? j1 : -1;
    yi[3] = (j1 + 1 > j0 + 1) ? j1 + 1 : -1;
#pragma unroll
    for (int k = 0; k < 4; ++k) {
        dx[k] = (xi[k] >= 0 && xi[k] < NBX) ? second_diff(xi[k], BSX, xmn, xmx) : 0.0f;
        dy[k] = (yi[k] >= 0 && yi[k] < NBY) ? second_diff(yi[k], BSY, ymn, ymx) : 0.0f;
    }

#pragma unroll
    for (int a = 0; a < 4; ++a) {
#pragma unroll
        for (int b = 0; b < 4; ++b) {
            float p = dx[a] * dy[b];
            if (p != 0.0f) {
                float2* cell = &Dr[xi[a] * NBY + yi[b]];
                atomicAdd(&cell->x, wh * p);
                atomicAdd(&cell->y, wv * p);
            }
        }
    }
}

// Fold K replicas + inclusive scan along y (inner dim) per row; result -> replica 0.
__global__ void __launch_bounds__(256) scan_rows(float2* __restrict__ D, int K) {
    __shared__ float bh[NBY];
    __shared__ float bv[NBY];
    int row = blockIdx.x;   // x index
    int y = threadIdx.x;
    float h = 0.0f, v = 0.0f;
    for (int k = 0; k < K; ++k) {
        float2 t = D[(size_t)k * NMAP + row * NBY + y];
        h += t.x;
        v += t.y;
    }
    bh[y] = h;
    bv[y] = v;
    __syncthreads();
    for (int off = 1; off < NBY; off <<= 1) {
        float ah = 0.0f, av = 0.0f;
        if (y >= off) { ah = bh[y - off]; av = bv[y - off]; }
        __syncthreads();
        bh[y] += ah;
        bv[y] += av;
        __syncthreads();
    }
    D[row * NBY + y] = make_float2(bh[y], bv[y]);
}

// Inclusive scan along x per column (one block per y) + fused finalize.
__global__ void __launch_bounds__(256) scan_cols_finalize(
    const float2* __restrict__ D,
    const float* __restrict__ init_h,
    const float* __restrict__ init_v,
    float* __restrict__ out) {
    __shared__ float bh[NBX];
    __shared__ float bv[NBX];
    int y = blockIdx.x;
    int x = threadIdx.x;
    float2 t = D[x * NBY + y];
    bh[x] = t.x;
    bv[x] = t.y;
    __syncthreads();
    for (int off = 1; off < NBX; off <<= 1) {
        float ah = 0.0f, av = 0.0f;
        if (x >= off) { ah = bh[x - off]; av = bv[x - off]; }
        __syncthreads();
        bh[x] += ah;
        bv[x] += av;
        __syncthreads();
    }
    int idx = x * NBY + y;
    float H = fmaf(bh[x], INV_H, init_h[idx]);
    float V = fmaf(bv[x], INV_V, init_v[idx]);
    float r = fmaxf(fabsf(H), fabsf(V));
    out[idx]            = r;
    out[idx + NMAP]     = H;
    out[idx + 2 * NMAP] = V;
}

extern "C" void kernel_launch(void* const* d_in, const int* in_sizes, int n_in,
                              void* d_out, int out_size, void* d_ws, size_t ws_size,
                              hipStream_t stream) {
    const float* pin_pos      = (const float*)d_in[0];
    const int*   netpin_start = (const int*)d_in[1];
    const int*   flat_netpin  = (const int*)d_in[2];
    const float* net_weights  = (const float*)d_in[3];
    const float* init_h       = (const float*)d_in[4];
    const float* init_v       = (const float*)d_in[5];
    float* out = (float*)d_out;

    int num_nets = in_sizes[3];           // net_weights length

    int K = (int)(ws_size / ((size_t)NMAP * sizeof(float2)));
    if (K > MAXK) K = MAXK;
    if (K < 1) K = 1;

    float2* D = (float2*)d_ws;            // K * 512 KiB scratch

    hipMemsetAsync(d_ws, 0, (size_t)K * NMAP * sizeof(float2), stream);

    int blocks = (num_nets + 255) / 256;
    net_scatter<<<blocks, 256, 0, stream>>>(pin_pos, netpin_start, flat_netpin,
                                            net_weights, D, num_nets, K);
    scan_rows<<<NBX, 256, 0, stream>>>(D, K);
    scan_cols_finalize<<<NBY, 256, 0, stream>>>(D, init_h, init_v, out);
}

// Round 4
// 185.333 us; speedup vs baseline: 1.5266x; 1.0047x over previous
//
#include <hip/hip_runtime.h>
#include <hip/hip_bf16.h>

// RUDY routing-demand maps via difference-domain scatter + 2D prefix sum.
// Each net deposits wt * u(x) ⊗ v(y); the first difference of the bin-overlap
// profile u has <=4 nonzeros, so each net scatters <=16 cells into a
// difference grid D; one inclusive scan per dimension reconstructs the maps.
//
// Round-4 change: round-3 counters showed WRITE_SIZE = 96 MB = 3.2M atomics
// x 32 B -> device-scope f32 atomics execute at the memory-side coherence
// point (per-XCD L2s non-coherent), capping us at ~8 atomics/clk device-wide.
// Fix: replica = physical XCC_ID and WORKGROUP-scope atomics, so the RMW
// stays in the XCD-local TCC (all writers of replica x are on XCD x by
// construction; TCC serializes RMWs; end-of-dispatch release flushes L2).

#define NBX 256
#define NBY 256
#define NMAP (NBX * NBY)
#define NXCD 8

__constant__ constexpr float BSX = 2.0f;
__constant__ constexpr float BSY = 2.0f;
// 1/(bin_area * UNIT_HCAP), 1/(bin_area * UNIT_VCAP)
__constant__ constexpr float INV_H = 1.0f / (4.0f * 50.0f);
__constant__ constexpr float INV_V = 1.0f / (4.0f * 40.0f);

// Cumulative overlap length of [mn,mx] with [XL, t], XL = 0.
__device__ __forceinline__ float seg_cum(float t, float mn, float mx) {
    return fminf(fmaxf(t, mn), mx) - mn;
}

// First difference of the per-bin overlap U(i) of [mn,mx] with bin i.
__device__ __forceinline__ float second_diff(int i, float bs, float mn, float mx) {
    float u2 = seg_cum((float)(i + 1) * bs, mn, mx);
    float u1 = seg_cum((float)(i) * bs, mn, mx);
    float u0 = seg_cum((float)(i - 1) * bs, mn, mx);
    return (u2 - u1) - (u1 - u0);
}

__device__ __forceinline__ int xcc_id() {
    unsigned v;
    asm volatile("s_getreg_b32 %0, hwreg(HW_REG_XCC_ID)" : "=s"(v));
    return (int)(v & (NXCD - 1));
}

template <bool XCD_LOCAL>
__global__ void __launch_bounds__(256) net_scatter(
    const float* __restrict__ pin_pos,
    const int* __restrict__ netpin_start,
    const int* __restrict__ flat_netpin,
    const float* __restrict__ net_weights,
    float2* __restrict__ D,   // replicas of interleaved {dH, dV} grid
    int num_nets, int K) {
    int n = blockIdx.x * blockDim.x + threadIdx.x;
    if (n >= num_nets) return;
    int s = netpin_start[n];
    int e = netpin_start[n + 1];
    if (e <= s) return;

    int rep = XCD_LOCAL ? xcc_id() : (blockIdx.x % K);
    float2* __restrict__ Dr = D + (size_t)rep * NMAP;

    float xmn = 3.0e38f, xmx = -3.0e38f, ymn = 3.0e38f, ymx = -3.0e38f;
    for (int p = s; p < e; ++p) {
        int ip = flat_netpin[p];
        float2 xy = *reinterpret_cast<const float2*>(pin_pos + 2 * (size_t)ip);
        xmn = fminf(xmn, xy.x);
        xmx = fmaxf(xmx, xy.x);
        ymn = fminf(ymn, xy.y);
        ymx = fmaxf(ymx, xy.y);
    }
    float w  = net_weights[n];
    float wh = w / (ymx - ymn);  // horizontal demand density
    float wv = w / (xmx - xmn);  // vertical demand density

    // Breakpoint bins (XL = YL = 0, bin size 2 -> *0.5)
    int i0 = (int)floorf(xmn * 0.5f);
    int i1 = (int)floorf(xmx * 0.5f);
    int j0 = (int)floorf(ymn * 0.5f);
    int j1 = (int)floorf(ymx * 0.5f);

    // Fixed 4-slot candidate lists (static indexing -> registers).
    int   xi[4], yi[4];
    float dx[4], dy[4];
    xi[0] = i0; xi[1] = i0 + 1;
    xi[2] = (i1 > i0 + 1) ? i1 : -1;
    xi[3] = (i1 + 1 > i0 + 1) ? i1 + 1 : -1;
    yi[0] = j0; yi[1] = j0 + 1;
    yi[2] = (j1 > j0 + 1) ? j1 : -1;
    yi[3] = (j1 + 1 > j0 + 1) ? j1 + 1 : -1;
#pragma unroll
    for (int k = 0; k < 4; ++k) {
        dx[k] = (xi[k] >= 0 && xi[k] < NBX) ? second_diff(xi[k], BSX, xmn, xmx) : 0.0f;
        dy[k] = (yi[k] >= 0 && yi[k] < NBY) ? second_diff(yi[k], BSY, ymn, ymx) : 0.0f;
    }

#pragma unroll
    for (int a = 0; a < 4; ++a) {
#pragma unroll
        for (int b = 0; b < 4; ++b) {
            float p = dx[a] * dy[b];
            if (p != 0.0f) {
                float2* cell = &Dr[xi[a] * NBY + yi[b]];
                if (XCD_LOCAL) {
                    // Workgroup-scope: no sc1 -> RMW executes in XCD-local TCC.
                    // Safe: every writer of this replica is on this XCD.
                    __hip_atomic_fetch_add(&cell->x, wh * p, __ATOMIC_RELAXED,
                                           __HIP_MEMORY_SCOPE_WORKGROUP);
                    __hip_atomic_fetch_add(&cell->y, wv * p, __ATOMIC_RELAXED,
                                           __HIP_MEMORY_SCOPE_WORKGROUP);
                } else {
                    atomicAdd(&cell->x, wh * p);
                    atomicAdd(&cell->y, wv * p);
                }
            }
        }
    }
}

// Fold K replicas + inclusive scan along y (inner dim) per row; result -> replica 0.
__global__ void __launch_bounds__(256) scan_rows(float2* __restrict__ D, int K) {
    __shared__ float bh[NBY];
    __shared__ float bv[NBY];
    int row = blockIdx.x;   // x index
    int y = threadIdx.x;
    float h = 0.0f, v = 0.0f;
    for (int k = 0; k < K; ++k) {
        float2 t = D[(size_t)k * NMAP + row * NBY + y];
        h += t.x;
        v += t.y;
    }
    bh[y] = h;
    bv[y] = v;
    __syncthreads();
    for (int off = 1; off < NBY; off <<= 1) {
        float ah = 0.0f, av = 0.0f;
        if (y >= off) { ah = bh[y - off]; av = bv[y - off]; }
        __syncthreads();
        bh[y] += ah;
        bv[y] += av;
        __syncthreads();
    }
    D[row * NBY + y] = make_float2(bh[y], bv[y]);
}

// Inclusive scan along x per column (one block per y) + fused finalize.
__global__ void __launch_bounds__(256) scan_cols_finalize(
    const float2* __restrict__ D,
    const float* __restrict__ init_h,
    const float* __restrict__ init_v,
    float* __restrict__ out) {
    __shared__ float bh[NBX];
    __shared__ float bv[NBX];
    int y = blockIdx.x;
    int x = threadIdx.x;
    float2 t = D[x * NBY + y];
    bh[x] = t.x;
    bv[x] = t.y;
    __syncthreads();
    for (int off = 1; off < NBX; off <<= 1) {
        float ah = 0.0f, av = 0.0f;
        if (x >= off) { ah = bh[x - off]; av = bv[x - off]; }
        __syncthreads();
        bh[x] += ah;
        bv[x] += av;
        __syncthreads();
    }
    int idx = x * NBY + y;
    float H = fmaf(bh[x], INV_H, init_h[idx]);
    float V = fmaf(bv[x], INV_V, init_v[idx]);
    float r = fmaxf(fabsf(H), fabsf(V));
    out[idx]            = r;
    out[idx + NMAP]     = H;
    out[idx + 2 * NMAP] = V;
}

extern "C" void kernel_launch(void* const* d_in, const int* in_sizes, int n_in,
                              void* d_out, int out_size, void* d_ws, size_t ws_size,
                              hipStream_t stream) {
    const float* pin_pos      = (const float*)d_in[0];
    const int*   netpin_start = (const int*)d_in[1];
    const int*   flat_netpin  = (const int*)d_in[2];
    const float* net_weights  = (const float*)d_in[3];
    const float* init_h       = (const float*)d_in[4];
    const float* init_v       = (const float*)d_in[5];
    float* out = (float*)d_out;

    int num_nets = in_sizes[3];           // net_weights length

    int K_avail = (int)(ws_size / ((size_t)NMAP * sizeof(float2)));
    bool xcd_mode = (K_avail >= NXCD);
    int K = xcd_mode ? NXCD : (K_avail < 1 ? 1 : K_avail);

    float2* D = (float2*)d_ws;            // K * 512 KiB scratch

    hipMemsetAsync(d_ws, 0, (size_t)K * NMAP * sizeof(float2), stream);

    int blocks = (num_nets + 255) / 256;
    if (xcd_mode) {
        net_scatter<true><<<blocks, 256, 0, stream>>>(
            pin_pos, netpin_start, flat_netpin, net_weights, D, num_nets, K);
    } else {
        net_scatter<false><<<blocks, 256, 0, stream>>>(
            pin_pos, netpin_start, flat_netpin, net_weights, D, num_nets, K);
    }
    scan_rows<<<NBX, 256, 0, stream>>>(D, K);
    scan_cols_finalize<<<NBY, 256, 0, stream>>>(D, init_h, init_v, out);
}